// Round 13
// baseline (392.694 us; speedup 1.0000x reference)
//
#include <hip/hip_runtime.h>
#include <hip/hip_bf16.h>

// out[b,s,h] = sum_d x[b,s,d] * W[cat[b],d,h] + bias[cat[b],h]
// Composition: ONE fused prepass dispatch (W transpose -> bf16 [C][N][K],
// x cast -> bf16 [B][S][K], batch counting-sort by expert) + 128x128
// 2-barrier MFMA GEMM with NON-TEMPORAL epilogue stores (R12: -23%).
// NEW vs R12: 32x32x16 MFMA (2495 TF ceiling vs 2176, half the instruction
// count) replacing 16x16x32. Staging/LDS/swizzle byte-identical to R12.

#define SEQ 512
#define DIN 1024
#define DH  4096
#define NCAT 16
#define NB   64
#define BK   64

typedef __attribute__((ext_vector_type(8)))  short   short8;
typedef __attribute__((ext_vector_type(8)))  __bf16  bf16x8;
typedef __attribute__((ext_vector_type(4)))  __bf16  bf16x4;
typedef __attribute__((ext_vector_type(4)))  float   f32x4;
typedef __attribute__((ext_vector_type(16))) float   f32x16;

static __device__ __forceinline__ void gload_lds16(const void* g, void* l) {
    __builtin_amdgcn_global_load_lds(
        (const __attribute__((address_space(1))) void*)g,
        (__attribute__((address_space(3))) void*)l,
        16, 0, 0);
}

#define MFMA_BF16(a, b, c) __builtin_amdgcn_mfma_f32_16x16x32_bf16((a), (b), (c), 0, 0, 0)
#define MFMA32(a, b, c)    __builtin_amdgcn_mfma_f32_32x32x16_bf16((a), (b), (c), 0, 0, 0)

// -------- fused prepass: W transpose + x cast + batch sort (one dispatch) ----
#define WBLK (16384)   // (DH/64) * (DIN/64) * NCAT
#define XBLK (2048)

__global__ __launch_bounds__(256)
void conv_all(const float* __restrict__ x, __bf16* __restrict__ xb,
              const float* __restrict__ W, __bf16* __restrict__ wt,
              const int* __restrict__ cat, int* __restrict__ perm) {
    const int t = threadIdx.x;
    if (blockIdx.x < WBLK) {
        // W [C][K][N] f32 -> Wt [C][N][K] bf16, 64x64 tile via padded LDS.
        __shared__ float lt[64][65];
        const unsigned wb = blockIdx.x;
        const int nb = (wb & 63) * 64;
        const int kb = ((wb >> 6) & 15) * 64;
        const int c  = wb >> 10;
        #pragma unroll
        for (int p = 0; p < 4; p++) {
            const int row = (t >> 4) + p * 16;
            const int col = (t & 15) * 4;
            const f32x4 v = __builtin_nontemporal_load(
                (const f32x4*)(W + ((size_t)c * DIN + kb + row) * DH + nb + col));
            lt[row][col] = v[0]; lt[row][col+1] = v[1];
            lt[row][col+2] = v[2]; lt[row][col+3] = v[3];
        }
        __syncthreads();
        #pragma unroll
        for (int p = 0; p < 2; p++) {
            const int n  = (t >> 3) + p * 32;
            const int k0 = (t & 7) * 8;
            bf16x8 h;
            #pragma unroll
            for (int j = 0; j < 8; j++) h[j] = (__bf16)lt[k0 + j][n];
            *(bf16x8*)(wt + ((size_t)c * DH + nb + n) * DIN + kb + k0) = h;
        }
    } else {
        if (blockIdx.x == WBLK && t == 0) {
            int cnt[NCAT];
            #pragma unroll
            for (int c = 0; c < NCAT; c++) cnt[c] = 0;
            for (int i = 0; i < NB; i++) cnt[cat[i]]++;
            int off[NCAT]; int s = 0;
            #pragma unroll
            for (int c = 0; c < NCAT; c++) { off[c] = s; s += cnt[c]; }
            for (int i = 0; i < NB; i++) perm[off[cat[i]]++] = i;
        }
        const int n8 = NB * SEQ * DIN / 8;
        int idx = (blockIdx.x - WBLK) * 256 + t;
        for (; idx < n8; idx += XBLK * 256) {
            const f32x4 a = __builtin_nontemporal_load(((const f32x4*)x) + (size_t)idx * 2);
            const f32x4 b = __builtin_nontemporal_load(((const f32x4*)x) + (size_t)idx * 2 + 1);
            bf16x8 h;
            h[0]=(__bf16)a[0]; h[1]=(__bf16)a[1]; h[2]=(__bf16)a[2]; h[3]=(__bf16)a[3];
            h[4]=(__bf16)b[0]; h[5]=(__bf16)b[1]; h[6]=(__bf16)b[2]; h[7]=(__bf16)b[3];
            ((bf16x8*)xb)[idx] = h;
        }
    }
}

// ------------- main GEMM: 128x128, BK=64, 32x32x16 MFMA -------------
// LDS layout + staging identical to R12 (verified, 0 conflicts): slot
// (row, g) holds source group g ^ (row&7); inverse-permuted global source.
// Frag (32x32x16): lane l holds 8 contiguous bf16 at row (l&31), k-half
// (l>>5)*8 — analog of the R1-verified 16x16 mapping.
// C/D: col = lane&31, row = (reg&3) + 8*(reg>>2) + 4*(lane>>5)  [m74/m101].
__global__ __launch_bounds__(256, 2)
void gemm_bt(const __bf16* __restrict__ xb, const int* __restrict__ cat_ids,
             const __bf16* __restrict__ wt, const float* __restrict__ bias,
             const int* __restrict__ perm, float* __restrict__ out) {
    __shared__ __align__(16) __bf16 lA[128 * 64];   // 16 KB
    __shared__ __align__(16) __bf16 lB[128 * 64];   // 16 KB

    const int t    = threadIdx.x;
    const int lane = t & 63;
    const int w    = t >> 6;
    const int wm   = (w >> 1) * 64;
    const int wn   = (w & 1) * 64;
    const int l31  = lane & 31;
    const int lh   = lane >> 5;     // k-half

    // Expert-grouped, locality-ordered grid + bijective XCD chunking.
    const unsigned o = blockIdx.x;
    const unsigned s = (o & 7) * (gridDim.x >> 3) + (o >> 3);
    const int bb  = perm[s >> 7];
    const int r   = s & 127;
    const int nb  = (r >> 2) * 128;
    const int mb  = (r & 3) * 128;
    const int c   = cat_ids[bb];

    const __bf16* xp = xb + ((size_t)bb * SEQ + mb) * DIN;
    const __bf16* wp = wt + ((size_t)c * DH + nb) * DIN;

    const int srow = lane >> 3;
    const int scol = ((lane & 7) ^ (lane >> 3)) * 8;

    f32x16 acc[2][2];
    #pragma unroll
    for (int i = 0; i < 2; i++)
        #pragma unroll
        for (int j = 0; j < 2; j++) acc[i][j] = (f32x16)0.f;

    for (int kt = 0; kt < DIN; kt += 64) {
        #pragma unroll
        for (int i = 0; i < 4; i++) {
            const int q = w * 4 + i;
            const int rr = q * 8 + srow;
            gload_lds16(xp + (size_t)rr * DIN + kt + scol, &lA[q * 512]);
            gload_lds16(wp + (size_t)rr * DIN + kt + scol, &lB[q * 512]);
        }
        __syncthreads();   // drains vmcnt(0): tiles resident + visible

        #pragma unroll
        for (int ks = 0; ks < 4; ks++) {            // 4 k-steps of 16
            const int kob = ks * 32 + lh * 16;      // byte offset of lane's 16B
            short8 bfv[2];
            #pragma unroll
            for (int fn = 0; fn < 2; fn++) {
                const int n = wn + fn * 32 + l31;
                bfv[fn] = *(const short8*)((const char*)lB +
                            (n * 128 + (kob ^ ((n & 7) << 4))));
            }
            #pragma unroll
            for (int fm = 0; fm < 2; fm++) {
                const int m = wm + fm * 32 + l31;
                const short8 af = *(const short8*)((const char*)lA +
                            (m * 128 + (kob ^ ((m & 7) << 4))));
                #pragma unroll
                for (int fn = 0; fn < 2; fn++)
                    acc[fm][fn] = MFMA32(af, bfv[fn], acc[fm][fn]);
            }
        }
        __syncthreads();   // reads done before next stage overwrites
    }

    // epilogue: col = lane&31, row = (reg&3)+8*(reg>>2)+4*lh; nt stores.
    const float* bp = bias + (size_t)c * DH;
    float*       op = out + (size_t)bb * SEQ * DH;
    #pragma unroll
    for (int fn = 0; fn < 2; fn++) {
        const int col = nb + wn + fn * 32 + l31;
        const float bv = bp[col];
        #pragma unroll
        for (int fm = 0; fm < 2; fm++) {
            const int row0 = mb + wm + fm * 32 + 4 * lh;
            #pragma unroll
            for (int reg = 0; reg < 16; reg++) {
                const int row = row0 + (reg & 3) + 8 * (reg >> 2);
                __builtin_nontemporal_store(acc[fm][fn][reg] + bv,
                                            &op[(size_t)row * DH + col]);
            }
        }
    }
}

// ---------------- fallback (ws too small): fused 128x128 ----------------
static __device__ __forceinline__ int swz_fb(int row) {
    return ((row ^ (row >> 3)) & 7) << 4;
}
__global__ __launch_bounds__(256, 2)
void cat_lin_fb(const float* __restrict__ x, const int* __restrict__ cat_ids,
                const float* __restrict__ W, const float* __restrict__ bias,
                float* __restrict__ out) {
    __shared__ unsigned char lAf[128 * 64 * 2];
    __shared__ unsigned char lBf[128 * 64 * 2];
    const int t = threadIdx.x, lane = t & 63, wave = t >> 6;
    const int wm = (wave >> 1) * 64, wn = (wave & 1) * 64;
    const int l15 = lane & 15, lg = lane >> 4;
    const int nb = blockIdx.x * 128, mb = blockIdx.y * 128, bb = blockIdx.z;
    const int c = cat_ids[bb];
    const float* xp = x + (size_t)bb * SEQ * DIN + (size_t)mb * DIN;
    const float* wp = W + (size_t)c * DIN * DH + nb;
    f32x4 acc[4][4];
    #pragma unroll
    for (int i = 0; i < 4; i++)
        #pragma unroll
        for (int j = 0; j < 4; j++) acc[i][j] = (f32x4)0.f;
    const int aM = t >> 4, aK = (t & 15) * 4;
    const int bN = (t & 31) * 4, bK = (t >> 5) * 4;
    for (int kt = 0; kt < DIN; kt += 64) {
        #pragma unroll
        for (int i = 0; i < 8; i++) {
            const int m = aM + i * 16;
            const f32x4 v = *(const f32x4*)(xp + (size_t)m * DIN + kt + aK);
            bf16x4 h;
            h[0]=(__bf16)v[0]; h[1]=(__bf16)v[1]; h[2]=(__bf16)v[2]; h[3]=(__bf16)v[3];
            *(bf16x4*)(&lAf[m * 128 + ((aK * 2) ^ swz_fb(m))]) = h;
        }
        #pragma unroll
        for (int i = 0; i < 2; i++) {
            const int k0 = bK + i * 32;
            const float* wr = wp + (size_t)(kt + k0) * DH + bN;
            const f32x4 r0 = *(const f32x4*)(wr);
            const f32x4 r1 = *(const f32x4*)(wr + DH);
            const f32x4 r2 = *(const f32x4*)(wr + 2 * (size_t)DH);
            const f32x4 r3 = *(const f32x4*)(wr + 3 * (size_t)DH);
            #pragma unroll
            for (int jj = 0; jj < 4; jj++) {
                bf16x4 h;
                h[0]=(__bf16)r0[jj]; h[1]=(__bf16)r1[jj];
                h[2]=(__bf16)r2[jj]; h[3]=(__bf16)r3[jj];
                const int n = bN + jj;
                *(bf16x4*)(&lBf[n * 128 + ((k0 * 2) ^ swz_fb(n))]) = h;
            }
        }
        __syncthreads();
        #pragma unroll
        for (int ks = 0; ks < 2; ks++) {
            const int kb2 = ks * 64 + lg * 16;
            short8 bfv[4];
            #pragma unroll
            for (int fn = 0; fn < 4; fn++) {
                const int n = wn + fn * 16 + l15;
                bfv[fn] = *(const short8*)(&lBf[n * 128 + (kb2 ^ swz_fb(n))]);
            }
            #pragma unroll
            for (int fm = 0; fm < 4; fm++) {
                const int m = wm + fm * 16 + l15;
                const short8 af = *(const short8*)(&lAf[m * 128 + (kb2 ^ swz_fb(m))]);
                #pragma unroll
                for (int fn = 0; fn < 4; fn++)
                    acc[fm][fn] = MFMA_BF16(af, bfv[fn], acc[fm][fn]);
            }
        }
        __syncthreads();
    }
    const float* bp = bias + (size_t)c * DH;
    float* op = out + (size_t)bb * SEQ * DH;
    #pragma unroll
    for (int fn = 0; fn < 4; fn++) {
        const int col = nb + wn + fn * 16 + l15;
        const float bv = bp[col];
        #pragma unroll
        for (int fm = 0; fm < 4; fm++) {
            const int row0 = mb + wm + fm * 16 + lg * 4;
            #pragma unroll
            for (int r = 0; r < 4; r++)
                op[(size_t)(row0 + r) * DH + col] = acc[fm][fn][r] + bv;
        }
    }
}

extern "C" void kernel_launch(void* const* d_in, const int* in_sizes, int n_in,
                              void* d_out, int out_size, void* d_ws, size_t ws_size,
                              hipStream_t stream) {
    const float* x   = (const float*)d_in[0];
    const int*   cid = (const int*)d_in[1];
    const float* W   = (const float*)d_in[2];
    const float* b   = (const float*)d_in[3];
    float*       out = (float*)d_out;

    const size_t xb_bytes = (size_t)NB * SEQ * DIN * 2;
    const size_t wt_bytes = (size_t)NCAT * DH * DIN * 2;

    if (ws_size >= xb_bytes + wt_bytes + 256) {
        __bf16* xbuf = (__bf16*)d_ws;
        __bf16* wbuf = (__bf16*)((char*)d_ws + xb_bytes);
        int*    perm = (int*)((char*)d_ws + xb_bytes + wt_bytes);
        conv_all<<<dim3(WBLK + XBLK), dim3(256), 0, stream>>>(x, xbuf, W, wbuf, cid, perm);
        gemm_bt<<<dim3(NB * (DH / 128) * (SEQ / 128)), dim3(256), 0, stream>>>(
            xbuf, cid, wbuf, b, perm, out);
    } else {
        dim3 gg(DH / 128, SEQ / 128, NB);
        cat_lin_fb<<<gg, 256, 0, stream>>>(x, cid, W, b, out);
    }
}

// Round 14
// 370.339 us; speedup vs baseline: 1.0604x; 1.0604x over previous
//
#include <hip/hip_runtime.h>
#include <hip/hip_bf16.h>

// out[b,s,h] = sum_d x[b,s,d] * W[cat[b],d,h] + bias[cat[b],h]
// FINAL (= R12, measured best 370.8 us): ONE fused prepass dispatch
// (W transpose -> bf16 [C][N][K], x cast -> bf16 [B][S][K], batch
// counting-sort by expert) + 128x128 2-barrier 16x16x32 MFMA GEMM
// (global_load_lds, both-sides XOR swizzle, expert-grouped XCD-chunked grid,
// NON-TEMPORAL epilogue stores). R13's 32x32 MFMA variant regressed
// (4-way LDS aliasing: 32-row frag reads vs 8 groups/row) -> reverted.

#define SEQ 512
#define DIN 1024
#define DH  4096
#define NCAT 16
#define NB   64
#define BK   64

typedef __attribute__((ext_vector_type(8))) short   short8;
typedef __attribute__((ext_vector_type(8))) __bf16  bf16x8;
typedef __attribute__((ext_vector_type(4))) __bf16  bf16x4;
typedef __attribute__((ext_vector_type(4))) float   f32x4;

static __device__ __forceinline__ void gload_lds16(const void* g, void* l) {
    __builtin_amdgcn_global_load_lds(
        (const __attribute__((address_space(1))) void*)g,
        (__attribute__((address_space(3))) void*)l,
        16, 0, 0);
}

#define MFMA_BF16(a, b, c) __builtin_amdgcn_mfma_f32_16x16x32_bf16((a), (b), (c), 0, 0, 0)

// -------- fused prepass: W transpose + x cast + batch sort (one dispatch) ----
#define WBLK (16384)   // (DH/64) * (DIN/64) * NCAT
#define XBLK (2048)

__global__ __launch_bounds__(256)
void conv_all(const float* __restrict__ x, __bf16* __restrict__ xb,
              const float* __restrict__ W, __bf16* __restrict__ wt,
              const int* __restrict__ cat, int* __restrict__ perm) {
    const int t = threadIdx.x;
    if (blockIdx.x < WBLK) {
        // W [C][K][N] f32 -> Wt [C][N][K] bf16, 64x64 tile via padded LDS.
        // W-f32 is read-once: non-temporal load (don't churn L3).
        __shared__ float lt[64][65];
        const unsigned wb = blockIdx.x;
        const int nb = (wb & 63) * 64;
        const int kb = ((wb >> 6) & 15) * 64;
        const int c  = wb >> 10;
        #pragma unroll
        for (int p = 0; p < 4; p++) {
            const int row = (t >> 4) + p * 16;
            const int col = (t & 15) * 4;
            const f32x4 v = __builtin_nontemporal_load(
                (const f32x4*)(W + ((size_t)c * DIN + kb + row) * DH + nb + col));
            lt[row][col] = v[0]; lt[row][col+1] = v[1];
            lt[row][col+2] = v[2]; lt[row][col+3] = v[3];
        }
        __syncthreads();
        #pragma unroll
        for (int p = 0; p < 2; p++) {
            const int n  = (t >> 3) + p * 32;
            const int k0 = (t & 7) * 8;
            bf16x8 h;
            #pragma unroll
            for (int j = 0; j < 8; j++) h[j] = (__bf16)lt[k0 + j][n];
            // normal store: wt is the GEMM's input, WANT it in L3
            *(bf16x8*)(wt + ((size_t)c * DH + nb + n) * DIN + kb + k0) = h;
        }
    } else {
        // stable counting sort of batches by category (thread 0 of one block)
        if (blockIdx.x == WBLK && t == 0) {
            int cnt[NCAT];
            #pragma unroll
            for (int c = 0; c < NCAT; c++) cnt[c] = 0;
            for (int i = 0; i < NB; i++) cnt[cat[i]]++;
            int off[NCAT]; int s = 0;
            #pragma unroll
            for (int c = 0; c < NCAT; c++) { off[c] = s; s += cnt[c]; }
            for (int i = 0; i < NB; i++) perm[off[cat[i]]++] = i;
        }
        // x f32 -> bf16 flat cast, grid-stride; x-f32 read-once -> nt load
        const int n8 = NB * SEQ * DIN / 8;
        int idx = (blockIdx.x - WBLK) * 256 + t;
        for (; idx < n8; idx += XBLK * 256) {
            const f32x4 a = __builtin_nontemporal_load(((const f32x4*)x) + (size_t)idx * 2);
            const f32x4 b = __builtin_nontemporal_load(((const f32x4*)x) + (size_t)idx * 2 + 1);
            bf16x8 h;
            h[0]=(__bf16)a[0]; h[1]=(__bf16)a[1]; h[2]=(__bf16)a[2]; h[3]=(__bf16)a[3];
            h[4]=(__bf16)b[0]; h[5]=(__bf16)b[1]; h[6]=(__bf16)b[2]; h[7]=(__bf16)b[3];
            ((bf16x8*)xb)[idx] = h;   // normal store: GEMM input, keep in L3
        }
    }
}

// ---------------- main GEMM: measured-best 128x128, BK=64 ----------------
// LDS slot (row, g) holds source group g ^ (row&7) (g = 16B group, 8/row);
// staged via inverse-permuted GLOBAL address, read with same XOR.
// Verified R3/R6/R9/R11/R12: 0 bank conflicts, VGPR 64, ~41% occupancy.
__global__ __launch_bounds__(256, 2)
void gemm_bt(const __bf16* __restrict__ xb, const int* __restrict__ cat_ids,
             const __bf16* __restrict__ wt, const float* __restrict__ bias,
             const int* __restrict__ perm, float* __restrict__ out) {
    __shared__ __align__(16) __bf16 lA[128 * 64];   // 16 KB
    __shared__ __align__(16) __bf16 lB[128 * 64];   // 16 KB

    const int t    = threadIdx.x;
    const int lane = t & 63;
    const int w    = t >> 6;
    const int wm   = (w >> 1) * 64;
    const int wn   = (w & 1) * 64;
    const int l15  = lane & 15;
    const int lg   = lane >> 4;

    // Expert-grouped, locality-ordered grid + bijective XCD chunking.
    // mb fastest (W-panel reuse x4), then nb sweep, then perm-ordered batch.
    const unsigned o = blockIdx.x;
    const unsigned s = (o & 7) * (gridDim.x >> 3) + (o >> 3);
    const int bb  = perm[s >> 7];
    const int r   = s & 127;
    const int nb  = (r >> 2) * 128;
    const int mb  = (r & 3) * 128;
    const int c   = cat_ids[bb];

    const __bf16* xp = xb + ((size_t)bb * SEQ + mb) * DIN;
    const __bf16* wp = wt + ((size_t)c * DH + nb) * DIN;

    const int srow = lane >> 3;
    const int scol = ((lane & 7) ^ (lane >> 3)) * 8;

    f32x4 acc[4][4];
    #pragma unroll
    for (int i = 0; i < 4; i++)
        #pragma unroll
        for (int j = 0; j < 4; j++) acc[i][j] = (f32x4)0.f;

    for (int kt = 0; kt < DIN; kt += 64) {
        #pragma unroll
        for (int i = 0; i < 4; i++) {
            const int q = w * 4 + i;
            const int rr = q * 8 + srow;
            gload_lds16(xp + (size_t)rr * DIN + kt + scol, &lA[q * 512]);
            gload_lds16(wp + (size_t)rr * DIN + kt + scol, &lB[q * 512]);
        }
        __syncthreads();   // drains vmcnt(0): tiles resident + visible

        #pragma unroll
        for (int ks = 0; ks < 2; ks++) {
            const int kob = (ks * 32 + lg * 8) * 2;
            short8 bfv[4];
            #pragma unroll
            for (int fn = 0; fn < 4; fn++) {
                const int n = wn + fn * 16 + l15;
                bfv[fn] = *(const short8*)((const char*)lB +
                            (n * 128 + (kob ^ ((n & 7) << 4))));
            }
            #pragma unroll
            for (int fm = 0; fm < 4; fm++) {
                const int m = wm + fm * 16 + l15;
                const short8 af = *(const short8*)((const char*)lA +
                            (m * 128 + (kob ^ ((m & 7) << 4))));
                #pragma unroll
                for (int fn = 0; fn < 4; fn++)
                    acc[fm][fn] = MFMA_BF16(af, bfv[fn], acc[fm][fn]);
            }
        }
        __syncthreads();   // reads done before next stage overwrites
    }

    // epilogue: D[row = lg*4 + r][col = l15]; NON-TEMPORAL stores (out is
    // write-once -> nt flag, keep L2/L3 for the GEMM inputs)
    const float* bp = bias + (size_t)c * DH;
    float*       op = out + (size_t)bb * SEQ * DH;
    #pragma unroll
    for (int fn = 0; fn < 4; fn++) {
        const int col = nb + wn + fn * 16 + l15;
        const float bv = bp[col];
        #pragma unroll
        for (int fm = 0; fm < 4; fm++) {
            const int row0 = mb + wm + fm * 16 + lg * 4;
            #pragma unroll
            for (int r2 = 0; r2 < 4; r2++)
                __builtin_nontemporal_store(acc[fm][fn][r2] + bv,
                                            &op[(size_t)(row0 + r2) * DH + col]);
        }
    }
}

// ---------------- fallback (ws too small): fused 128x128 ----------------
static __device__ __forceinline__ int swz_fb(int row) {
    return ((row ^ (row >> 3)) & 7) << 4;
}
__global__ __launch_bounds__(256, 2)
void cat_lin_fb(const float* __restrict__ x, const int* __restrict__ cat_ids,
                const float* __restrict__ W, const float* __restrict__ bias,
                float* __restrict__ out) {
    __shared__ unsigned char lAf[128 * 64 * 2];
    __shared__ unsigned char lBf[128 * 64 * 2];
    const int t = threadIdx.x, lane = t & 63, wave = t >> 6;
    const int wm = (wave >> 1) * 64, wn = (wave & 1) * 64;
    const int l15 = lane & 15, lg = lane >> 4;
    const int nb = blockIdx.x * 128, mb = blockIdx.y * 128, bb = blockIdx.z;
    const int c = cat_ids[bb];
    const float* xp = x + (size_t)bb * SEQ * DIN + (size_t)mb * DIN;
    const float* wp = W + (size_t)c * DIN * DH + nb;
    f32x4 acc[4][4];
    #pragma unroll
    for (int i = 0; i < 4; i++)
        #pragma unroll
        for (int j = 0; j < 4; j++) acc[i][j] = (f32x4)0.f;
    const int aM = t >> 4, aK = (t & 15) * 4;
    const int bN = (t & 31) * 4, bK = (t >> 5) * 4;
    for (int kt = 0; kt < DIN; kt += 64) {
        #pragma unroll
        for (int i = 0; i < 8; i++) {
            const int m = aM + i * 16;
            const f32x4 v = *(const f32x4*)(xp + (size_t)m * DIN + kt + aK);
            bf16x4 h;
            h[0]=(__bf16)v[0]; h[1]=(__bf16)v[1]; h[2]=(__bf16)v[2]; h[3]=(__bf16)v[3];
            *(bf16x4*)(&lAf[m * 128 + ((aK * 2) ^ swz_fb(m))]) = h;
        }
        #pragma unroll
        for (int i = 0; i < 2; i++) {
            const int k0 = bK + i * 32;
            const float* wr = wp + (size_t)(kt + k0) * DH + bN;
            const f32x4 r0 = *(const f32x4*)(wr);
            const f32x4 r1 = *(const f32x4*)(wr + DH);
            const f32x4 r2 = *(const f32x4*)(wr + 2 * (size_t)DH);
            const f32x4 r3 = *(const f32x4*)(wr + 3 * (size_t)DH);
            #pragma unroll
            for (int jj = 0; jj < 4; jj++) {
                bf16x4 h;
                h[0]=(__bf16)r0[jj]; h[1]=(__bf16)r1[jj];
                h[2]=(__bf16)r2[jj]; h[3]=(__bf16)r3[jj];
                const int n = bN + jj;
                *(bf16x4*)(&lBf[n * 128 + ((k0 * 2) ^ swz_fb(n))]) = h;
            }
        }
        __syncthreads();
        #pragma unroll
        for (int ks = 0; ks < 2; ks++) {
            const int kb2 = ks * 64 + lg * 16;
            short8 bfv[4];
            #pragma unroll
            for (int fn = 0; fn < 4; fn++) {
                const int n = wn + fn * 16 + l15;
                bfv[fn] = *(const short8*)(&lBf[n * 128 + (kb2 ^ swz_fb(n))]);
            }
            #pragma unroll
            for (int fm = 0; fm < 4; fm++) {
                const int m = wm + fm * 16 + l15;
                const short8 af = *(const short8*)(&lAf[m * 128 + (kb2 ^ swz_fb(m))]);
                #pragma unroll
                for (int fn = 0; fn < 4; fn++)
                    acc[fm][fn] = MFMA_BF16(af, bfv[fn], acc[fm][fn]);
            }
        }
        __syncthreads();
    }
    const float* bp = bias + (size_t)c * DH;
    float* op = out + (size_t)bb * SEQ * DH;
    #pragma unroll
    for (int fn = 0; fn < 4; fn++) {
        const int col = nb + wn + fn * 16 + l15;
        const float bv = bp[col];
        #pragma unroll
        for (int fm = 0; fm < 4; fm++) {
            const int row0 = mb + wm + fm * 16 + lg * 4;
            #pragma unroll
            for (int r = 0; r < 4; r++)
                op[(size_t)(row0 + r) * DH + col] = acc[fm][fn][r] + bv;
        }
    }
}

extern "C" void kernel_launch(void* const* d_in, const int* in_sizes, int n_in,
                              void* d_out, int out_size, void* d_ws, size_t ws_size,
                              hipStream_t stream) {
    const float* x   = (const float*)d_in[0];
    const int*   cid = (const int*)d_in[1];
    const float* W   = (const float*)d_in[2];
    const float* b   = (const float*)d_in[3];
    float*       out = (float*)d_out;

    const size_t xb_bytes = (size_t)NB * SEQ * DIN * 2;
    const size_t wt_bytes = (size_t)NCAT * DH * DIN * 2;

    if (ws_size >= xb_bytes + wt_bytes + 256) {
        __bf16* xbuf = (__bf16*)d_ws;
        __bf16* wbuf = (__bf16*)((char*)d_ws + xb_bytes);
        int*    perm = (int*)((char*)d_ws + xb_bytes + wt_bytes);
        conv_all<<<dim3(WBLK + XBLK), dim3(256), 0, stream>>>(x, xbuf, W, wbuf, cid, perm);
        gemm_bt<<<dim3(NB * (DH / 128) * (SEQ / 128)), dim3(256), 0, stream>>>(
            xbuf, cid, wbuf, b, perm, out);
    } else {
        dim3 gg(DH / 128, SEQ / 128, NB);
        cat_lin_fb<<<gg, 256, 0, stream>>>(x, cid, W, b, out);
    }
}